// Round 15
// baseline (30.306 us; speedup 1.0000x reference)
//
#include <hip/hip_runtime.h>

#define E  9
#define B_ 8
#define H_ 224
#define W_ 224
#define C_ 32
#define TH 7                        // rows per thread
#define WT 8                        // w pixels per block (256 thr = 32 ch x 8 w)
#define STRIPS (H_ / TH)            // 32
#define WTILES (W_ / WT)            // 28
#define NBLK (B_ * STRIPS * WTILES) // 7168 = exactly 28 blocks/CU, %8==0

__global__ __launch_bounds__(256) void fm_main(const float* __restrict__ inp,
                                               const float* __restrict__ kern,
                                               const float* __restrict__ mask,
                                               float* __restrict__ out) {
    int t = threadIdx.x;

    // Bijective XCD-chunk swizzle (896 blocks per XCD).
    int bid = blockIdx.x;
    int swz = (bid & 7) * (NBLK / 8) + (bid >> 3);
    int bw  = swz % WTILES;
    int t2  = swz / WTILES;
    int hs  = (t2 % STRIPS) * TH;   // strip start row
    int b   = t2 / STRIPS;

    int c  = t & 31;                // channel (lane-contiguous -> coalesced)
    int wl = t >> 5;                // 0..7
    int w  = bw * WT + wl;

    // ---- Coefficients: 18 scalars/thread. This fits UNDER the allocator's
    // ~64-80 VGPR comfort zone (R12/R13 proved a 72-float set gets spilled to
    // scratch despite pins; redelivery ~924 MB/launch was the 30 us plateau).
    float cm[E], ck[E];
    float mx = 0.f;
#pragma unroll
    for (int e = 0; e < E; ++e) {
        float mv = fabsf(mask[e * C_ + c]);
        ck[e] = kern[e * C_ + c];
        mx = fmaxf(mx, mv);
        cm[e] = mv;
    }
    // lanes 0..31 of each half-wave cover all 32 channels -> 5-step butterfly
    mx = fmaxf(mx, __shfl_xor(mx, 1));
    mx = fmaxf(mx, __shfl_xor(mx, 2));
    mx = fmaxf(mx, __shfl_xor(mx, 4));
    mx = fmaxf(mx, __shfl_xor(mx, 8));
    mx = fmaxf(mx, __shfl_xor(mx, 16));
    float inv = 1.f / (mx + 1e-6f);
#pragma unroll
    for (int e = 0; e < E; ++e) cm[e] *= inv;
    // "+v": opaque, non-rematerializable; small enough to stay resident.
#pragma unroll
    for (int e = 0; e < E; ++e)
        asm volatile("" : "+v"(cm[e]), "+v"(ck[e]));

    const float* base = inp + (((size_t)b * H_ * W_ + w) * C_) + c;
    bool wm = (w > 0);
    bool wp = (w < W_ - 1);

    float win[3][3];   // rolling 3-row window of scalar taps [slot][x -1,0,+1]

    auto ld3 = [&](int hh, float* r) {
        if ((unsigned)hh < (unsigned)H_) {   // block-uniform branch
            const float* p = base + (size_t)hh * (W_ * C_);
            r[0] = wm ? p[-C_] : 0.f;
            r[1] = p[0];
            r[2] = wp ? p[C_] : 0.f;
        } else {
            r[0] = 0.f; r[1] = 0.f; r[2] = 0.f;
        }
    };

    ld3(hs - 1, win[0]);
    ld3(hs,     win[1]);

    const float inv9 = 1.f / 9.f;

#pragma unroll
    for (int s = 0; s < TH; ++s) {
        ld3(hs + s + 1, win[(s + 2) % 3]);

        const float* rm1 = win[(s + 0) % 3];   // row h-1
        const float* r0  = win[(s + 1) % 3];   // row h
        const float* rp1 = win[(s + 2) % 3];   // row h+1

        // tap order: e=0 center, then (y,x) raster skipping center
        float taps[E] = { r0[1],
                          rm1[0], rm1[1], rm1[2],
                          r0[0],          r0[2],
                          rp1[0], rp1[1], rp1[2] };

        float d[E];
        float n = 0.f, sm = 0.f;
#pragma unroll
        for (int e = 0; e < E; ++e) {
            float dd = fmaf(taps[e], cm[e], -ck[e]);
            d[e] = dd;
            n  += fabsf(dd);     // abs folds as src modifier
            sm += dd;
        }
        float nm = sm * (-inv9);
        float v = 0.f;
#pragma unroll
        for (int e = 0; e < E; ++e)
            v += fabsf(fabsf(d[e]) + nm);

        float o = fmaf(v, -inv9, 1.f) * fmaf(n, -inv9, 1.f);

        // write-once/never-read: non-temporal bypasses L2/L3
        float* op = out + (((size_t)b * H_ + (hs + s)) * W_ + w) * C_ + c;
        __builtin_nontemporal_store(o, op);
    }
}

extern "C" void kernel_launch(void* const* d_in, const int* in_sizes, int n_in,
                              void* d_out, int out_size, void* d_ws, size_t ws_size,
                              hipStream_t stream) {
    const float* inp  = (const float*)d_in[0];
    const float* kern = (const float*)d_in[1];
    const float* mask = (const float*)d_in[2];
    float* out = (float*)d_out;

    fm_main<<<NBLK, 256, 0, stream>>>(inp, kern, mask, out);
}

// Round 16
// 27.562 us; speedup vs baseline: 1.0996x; 1.0996x over previous
//
#include <hip/hip_runtime.h>

#define E  9
#define B_ 8
#define H_ 224
#define W_ 224
#define C_ 32
#define TH 7                        // rows per thread
#define WT 8                        // w pixels per block (256 thr = 32 ch x 8 w)
#define STRIPS (H_ / TH)            // 32
#define WTILES (W_ / WT)            // 28
#define NBLK (B_ * STRIPS * WTILES) // 7168 = 28 blocks/CU, %8==0

__global__ __launch_bounds__(256)
__attribute__((amdgpu_waves_per_eu(4, 4)))   // 128-VGPR budget: room for the
                                             // 27-tap + 63-d resident set
void fm_main(const float* __restrict__ inp,
             const float* __restrict__ kern,
             const float* __restrict__ mask,
             float* __restrict__ out) {
    int t = threadIdx.x;

    // Bijective XCD-chunk swizzle (896 blocks per XCD).
    int bid = blockIdx.x;
    int swz = (bid & 7) * (NBLK / 8) + (bid >> 3);
    int bw  = swz % WTILES;
    int t2  = swz / WTILES;
    int hs  = (t2 % STRIPS) * TH;   // strip start row
    int b   = t2 / STRIPS;

    int c  = t & 31;                // channel (lane-contiguous -> coalesced)
    int wl = t >> 5;                // 0..7
    int w  = bw * WT + wl;

    const float* base = inp + (((size_t)b * H_ * W_ + w) * C_) + c;
    bool wm = (w > 0);
    bool wp = (w < W_ - 1);

    // ---- Tap prologue: ALL (TH+2) x 3 taps into registers up front.
    // e-outer below streams coefficients ONCE per strip instead of once per
    // row: R9-R14's invariant ~30us wall was the compiler rederiving the
    // coeff set every row (~923 MB/launch through the per-CU L1/LDS return
    // path). Taps, unlike coeffs, cannot be rematerialized -> they stay put.
    float tap[TH + 2][3];
#pragma unroll
    for (int r = 0; r < TH + 2; ++r) {
        int hh = hs - 1 + r;
        if ((unsigned)hh < (unsigned)H_) {   // block-uniform branch
            const float* p = base + (size_t)hh * (W_ * C_);
            tap[r][0] = wm ? p[-C_] : 0.f;
            tap[r][1] = p[0];
            tap[r][2] = wp ? p[C_] : 0.f;
        } else {
            tap[r][0] = 0.f; tap[r][1] = 0.f; tap[r][2] = 0.f;
        }
    }

    // ---- absmax(|mask|): lanes 0..31 cover all 32 channels.
    float mv[E];
    float mx = 0.f;
#pragma unroll
    for (int e = 0; e < E; ++e) {
        mv[e] = fabsf(mask[e * C_ + c]);
        mx = fmaxf(mx, mv[e]);
    }
    mx = fmaxf(mx, __shfl_xor(mx, 1));
    mx = fmaxf(mx, __shfl_xor(mx, 2));
    mx = fmaxf(mx, __shfl_xor(mx, 4));
    mx = fmaxf(mx, __shfl_xor(mx, 8));
    mx = fmaxf(mx, __shfl_xor(mx, 16));
    float inv = 1.f / (mx + 1e-6f);

    // tap order: e=0 center, then (y,x) raster skipping center
    const int dyA[E] = {0, -1, -1, -1, 0, 0, 1, 1, 1};
    const int dxA[E] = {0, -1,  0,  1, -1, 1, -1, 0, 1};

    const float inv9 = 1.f / 9.f;

    float n[TH], sm[TH], dd[E][TH];
#pragma unroll
    for (int s = 0; s < TH; ++s) { n[s] = 0.f; sm[s] = 0.f; }

    // ---- Pass 1: e-outer. Each e loads its 2 coefficients ONCE, sweeps rows.
#pragma unroll
    for (int e = 0; e < E; ++e) {
        float m = mv[e] * inv;
        float k = kern[e * C_ + c];
#pragma unroll
        for (int s = 0; s < TH; ++s) {
            float d0 = fmaf(tap[s + 1 + dyA[e]][1 + dxA[e]], m, -k);
            dd[e][s] = d0;
            n[s]  += fabsf(d0);     // abs as src modifier
            sm[s] += d0;
        }
    }

    // ---- Pass 2: finalize each row and store.
#pragma unroll
    for (int s = 0; s < TH; ++s) {
        float nm = sm[s] * (-inv9);
        float v = 0.f;
#pragma unroll
        for (int e = 0; e < E; ++e)
            v += fabsf(fabsf(dd[e][s]) + nm);

        float o = fmaf(v, -inv9, 1.f) * fmaf(n[s], -inv9, 1.f);

        // write-once/never-read: non-temporal bypasses L2/L3
        float* op = out + (((size_t)b * H_ + (hs + s)) * W_ + w) * C_ + c;
        __builtin_nontemporal_store(o, op);
    }
}

extern "C" void kernel_launch(void* const* d_in, const int* in_sizes, int n_in,
                              void* d_out, int out_size, void* d_ws, size_t ws_size,
                              hipStream_t stream) {
    const float* inp  = (const float*)d_in[0];
    const float* kern = (const float*)d_in[1];
    const float* mask = (const float*)d_in[2];
    float* out = (float*)d_out;

    fm_main<<<NBLK, 256, 0, stream>>>(inp, kern, mask, out);
}

// Round 17
// 26.009 us; speedup vs baseline: 1.1652x; 1.0597x over previous
//
#include <hip/hip_runtime.h>

#define E  9
#define B_ 8
#define H_ 224
#define W_ 224
#define C_ 32
#define TH 7                        // rows per thread
#define WT 8                        // w pixels per block (256 thr = 32 ch x 8 w)
#define STRIPS (H_ / TH)            // 32
#define WTILES (W_ / WT)            // 28
#define NBLK (B_ * STRIPS * WTILES) // 7168 = 28 blocks/CU, %8==0

__global__ __launch_bounds__(256) void fm_main(const float* __restrict__ inp,
                                               const float* __restrict__ kern,
                                               const float* __restrict__ mask,
                                               float* __restrict__ out) {
    int t = threadIdx.x;

    // Bijective XCD-chunk swizzle (896 blocks per XCD).
    int bid = blockIdx.x;
    int swz = (bid & 7) * (NBLK / 8) + (bid >> 3);
    int bw  = swz % WTILES;
    int t2  = swz / WTILES;
    int hs  = (t2 % STRIPS) * TH;   // strip start row
    int b   = t2 / STRIPS;

    int c  = t & 31;                // channel (lane-contiguous -> coalesced)
    int wl = t >> 5;                // 0..7
    int w  = bw * WT + wl;

    const float* base = inp + (((size_t)b * H_ * W_ + w) * C_) + c;
    bool wm = (w > 0);
    bool wp = (w < W_ - 1);

    // ---- Tap prologue: ALL (TH+2) x 3 taps into registers up front.
    // e-outer coefficient streaming (R15) removed the per-row coeff
    // redelivery that was the 30us plateau. This round: drop the dd[9][7]
    // store (was ~63 VGPRs -> 4 waves/SIMD cap); pass 2 recomputes d from
    // the resident taps instead. Live set ~60 regs -> 6-8 waves/SIMD.
    float tap[TH + 2][3];
#pragma unroll
    for (int r = 0; r < TH + 2; ++r) {
        int hh = hs - 1 + r;
        if ((unsigned)hh < (unsigned)H_) {   // block-uniform branch
            const float* p = base + (size_t)hh * (W_ * C_);
            tap[r][0] = wm ? p[-C_] : 0.f;
            tap[r][1] = p[0];
            tap[r][2] = wp ? p[C_] : 0.f;
        } else {
            tap[r][0] = 0.f; tap[r][1] = 0.f; tap[r][2] = 0.f;
        }
    }

    // ---- absmax(|mask|): lanes 0..31 cover all 32 channels.
    float mv[E];
    float mx = 0.f;
#pragma unroll
    for (int e = 0; e < E; ++e) {
        mv[e] = fabsf(mask[e * C_ + c]);
        mx = fmaxf(mx, mv[e]);
    }
    mx = fmaxf(mx, __shfl_xor(mx, 1));
    mx = fmaxf(mx, __shfl_xor(mx, 2));
    mx = fmaxf(mx, __shfl_xor(mx, 4));
    mx = fmaxf(mx, __shfl_xor(mx, 8));
    mx = fmaxf(mx, __shfl_xor(mx, 16));
    float inv = 1.f / (mx + 1e-6f);

    float cm[E], ck[E];
#pragma unroll
    for (int e = 0; e < E; ++e) {
        cm[e] = mv[e] * inv;
        ck[e] = kern[e * C_ + c];
    }

    // tap order: e=0 center, then (y,x) raster skipping center
    const int dyA[E] = {0, -1, -1, -1, 0, 0, 1, 1, 1};
    const int dxA[E] = {0, -1,  0,  1, -1, 1, -1, 0, 1};

    const float inv9 = 1.f / 9.f;

    float n[TH], sm[TH];
#pragma unroll
    for (int s = 0; s < TH; ++s) { n[s] = 0.f; sm[s] = 0.f; }

    // ---- Pass 1: e-outer, accumulate n and sum only (no d storage).
#pragma unroll
    for (int e = 0; e < E; ++e) {
        float m = cm[e], k = ck[e];
#pragma unroll
        for (int s = 0; s < TH; ++s) {
            float d0 = fmaf(tap[s + 1 + dyA[e]][1 + dxA[e]], m, -k);
            n[s]  += fabsf(d0);     // abs as src modifier
            sm[s] += d0;
        }
    }

    // ---- Pass 2: recompute d per (e,s) from resident taps; finalize rows.
#pragma unroll
    for (int s = 0; s < TH; ++s) {
        float nm = sm[s] * (-inv9);
        float v = 0.f;
#pragma unroll
        for (int e = 0; e < E; ++e) {
            float d0 = fmaf(tap[s + 1 + dyA[e]][1 + dxA[e]], cm[e], -ck[e]);
            v += fabsf(fabsf(d0) + nm);
        }

        float o = fmaf(v, -inv9, 1.f) * fmaf(n[s], -inv9, 1.f);

        // write-once/never-read: non-temporal bypasses L2/L3
        float* op = out + (((size_t)b * H_ + (hs + s)) * W_ + w) * C_ + c;
        __builtin_nontemporal_store(o, op);
    }
}

extern "C" void kernel_launch(void* const* d_in, const int* in_sizes, int n_in,
                              void* d_out, int out_size, void* d_ws, size_t ws_size,
                              hipStream_t stream) {
    const float* inp  = (const float*)d_in[0];
    const float* kern = (const float*)d_in[1];
    const float* mask = (const float*)d_in[2];
    float* out = (float*)d_out;

    fm_main<<<NBLK, 256, 0, stream>>>(inp, kern, mask, out);
}

// Round 18
// 25.090 us; speedup vs baseline: 1.2079x; 1.0366x over previous
//
#include <hip/hip_runtime.h>

#define E  9
#define B_ 8
#define H_ 224
#define W_ 224
#define C_ 32
#define TH 7                        // rows per thread
#define TW 2                        // w pixels per thread
#define WT 16                       // w pixels per block (8 w-pairs x 32 ch)
#define STRIPS (H_ / TH)            // 32
#define WTILES (W_ / WT)            // 14
#define NBLK (B_ * STRIPS * WTILES) // 3584 = 14 blocks/CU, %8==0

__global__ __launch_bounds__(256) void fm_main(const float* __restrict__ inp,
                                               const float* __restrict__ kern,
                                               const float* __restrict__ mask,
                                               float* __restrict__ out) {
    int t = threadIdx.x;

    // Bijective XCD-chunk swizzle (448 blocks per XCD).
    int bid = blockIdx.x;
    int swz = (bid & 7) * (NBLK / 8) + (bid >> 3);
    int bw  = swz % WTILES;
    int t2  = swz / WTILES;
    int hs  = (t2 % STRIPS) * TH;   // strip start row
    int b   = t2 / STRIPS;

    int c  = t & 31;                // channel (lane-contiguous -> coalesced)
    int wg = t >> 5;                // 0..7 -> w-pair
    int w0 = bw * WT + wg * TW;     // first of 2 owned w positions

    const float* base = inp + (((size_t)b * H_ * W_ + w0) * C_) + c;
    bool wm = (w0 > 0);             // col w0-1 exists
    bool wp = (w0 + TW < W_);       // col w0+2 exists

    // ---- Tap prologue: (TH+2) x (TW+2) taps -> registers.
    // R15/R16 fixed coeff redelivery (e-outer); this round cuts the x-halo:
    // 2 output columns share their 4 tap columns -> 2.57 loads/elem (was 3.86).
    float tap[TH + 2][TW + 2];
#pragma unroll
    for (int r = 0; r < TH + 2; ++r) {
        int hh = hs - 1 + r;
        if ((unsigned)hh < (unsigned)H_) {   // block-uniform branch
            const float* p = base + (size_t)hh * (W_ * C_);
            tap[r][0] = wm ? p[-C_] : 0.f;
            tap[r][1] = p[0];
            tap[r][2] = p[C_];               // w0+1 always < W_ (output col)
            tap[r][3] = wp ? p[2 * C_] : 0.f;
        } else {
#pragma unroll
            for (int j = 0; j < TW + 2; ++j) tap[r][j] = 0.f;
        }
    }

    // ---- absmax(|mask|): lanes 0..31 cover all 32 channels.
    float mv[E];
    float mx = 0.f;
#pragma unroll
    for (int e = 0; e < E; ++e) {
        mv[e] = fabsf(mask[e * C_ + c]);
        mx = fmaxf(mx, mv[e]);
    }
    mx = fmaxf(mx, __shfl_xor(mx, 1));
    mx = fmaxf(mx, __shfl_xor(mx, 2));
    mx = fmaxf(mx, __shfl_xor(mx, 4));
    mx = fmaxf(mx, __shfl_xor(mx, 8));
    mx = fmaxf(mx, __shfl_xor(mx, 16));
    float inv = 1.f / (mx + 1e-6f);

    float cm[E], ck[E];
#pragma unroll
    for (int e = 0; e < E; ++e) {
        cm[e] = mv[e] * inv;
        ck[e] = kern[e * C_ + c];
    }

    // tap order: e=0 center, then (y,x) raster skipping center
    const int dyA[E] = {0, -1, -1, -1, 0, 0, 1, 1, 1};
    const int dxA[E] = {0, -1,  0,  1, -1, 1, -1, 0, 1};

    const float inv9 = 1.f / 9.f;

    float n[TH][TW], sm[TH][TW];
#pragma unroll
    for (int s = 0; s < TH; ++s)
#pragma unroll
        for (int j = 0; j < TW; ++j) { n[s][j] = 0.f; sm[s][j] = 0.f; }

    // ---- Pass 1: e-outer, accumulate n and sum (no d storage).
#pragma unroll
    for (int e = 0; e < E; ++e) {
        float m = cm[e], k = ck[e];
#pragma unroll
        for (int s = 0; s < TH; ++s) {
#pragma unroll
            for (int j = 0; j < TW; ++j) {
                float d0 = fmaf(tap[s + 1 + dyA[e]][1 + j + dxA[e]], m, -k);
                n[s][j]  += fabsf(d0);   // abs as src modifier
                sm[s][j] += d0;
            }
        }
    }

    // ---- Pass 2: recompute d from resident taps; finalize and store.
#pragma unroll
    for (int s = 0; s < TH; ++s) {
        float nm0 = sm[s][0] * (-inv9);
        float nm1 = sm[s][1] * (-inv9);
        float v0 = 0.f, v1 = 0.f;
#pragma unroll
        for (int e = 0; e < E; ++e) {
            float d0 = fmaf(tap[s + 1 + dyA[e]][1 + dxA[e]],     cm[e], -ck[e]);
            float d1 = fmaf(tap[s + 1 + dyA[e]][2 + dxA[e]],     cm[e], -ck[e]);
            v0 += fabsf(fabsf(d0) + nm0);
            v1 += fabsf(fabsf(d1) + nm1);
        }

        float o0 = fmaf(v0, -inv9, 1.f) * fmaf(n[s][0], -inv9, 1.f);
        float o1 = fmaf(v1, -inv9, 1.f) * fmaf(n[s][1], -inv9, 1.f);

        // write-once/never-read: non-temporal bypasses L2/L3
        float* op = out + (((size_t)b * H_ + (hs + s)) * W_ + w0) * C_ + c;
        __builtin_nontemporal_store(o0, op);
        __builtin_nontemporal_store(o1, op + C_);
    }
}

extern "C" void kernel_launch(void* const* d_in, const int* in_sizes, int n_in,
                              void* d_out, int out_size, void* d_ws, size_t ws_size,
                              hipStream_t stream) {
    const float* inp  = (const float*)d_in[0];
    const float* kern = (const float*)d_in[1];
    const float* mask = (const float*)d_in[2];
    float* out = (float*)d_out;

    fm_main<<<NBLK, 256, 0, stream>>>(inp, kern, mask, out);
}